// Round 6
// baseline (155.281 us; speedup 1.0000x reference)
//
#include <hip/hip_runtime.h>
#include <math.h>

#define BROWS 8192
#define DIMS  256
#define ATTRS 4
#define TIR 64              // valid (gathered) rows per tile
#define TJC 64              // cols per tile
#define COLT (BROWS / TJC)  // 128 col tiles
#define GEMM_BLOCKS 1024

typedef __bf16 bf16x8 __attribute__((ext_vector_type(8)));
typedef __bf16 bf16x4 __attribute__((ext_vector_type(4)));
typedef float  f32x4  __attribute__((ext_vector_type(4)));

constexpr float INV_T = 1.0f / 0.07f;

// ---------- kernel 1: normalize rows -> bf16 + flag all-ones rows --------------
__global__ __launch_bounds__(256)
void prep_kernel(const float* __restrict__ z, const float* __restrict__ attr,
                 __bf16* __restrict__ zh,
                 int* __restrict__ flags, int* __restrict__ onelist,
                 int* __restrict__ count,
                 float* __restrict__ pos_sum, float* __restrict__ all_sum) {
    const int t = threadIdx.x;
    const int lane = t & 63;
    const int row = blockIdx.x * 4 + (t >> 6);   // one wave per row

    const float4 v = *reinterpret_cast<const float4*>(&z[(size_t)row * DIMS + lane * 4]);
    float ss = v.x * v.x + v.y * v.y + v.z * v.z + v.w * v.w;
    #pragma unroll
    for (int m = 32; m >= 1; m >>= 1) ss += __shfl_xor(ss, m);
    const float norm = fmaxf(sqrtf(ss), 1e-12f);

    bf16x4 hv = {(__bf16)(v.x / norm), (__bf16)(v.y / norm),
                 (__bf16)(v.z / norm), (__bf16)(v.w / norm)};
    *reinterpret_cast<bf16x4*>(&zh[(size_t)row * DIMS + lane * 4]) = hv;

    if (lane == 0) {
        pos_sum[row] = 0.0f;                     // ws is poisoned each call
        all_sum[row] = 0.0f;
        const float4 a = *reinterpret_cast<const float4*>(&attr[(size_t)row * ATTRS]);
        const bool one = (a.x == 1.0f) && (a.y == 1.0f) && (a.z == 1.0f) && (a.w == 1.0f);
        flags[row] = one ? 1 : 0;
        if (one) onelist[atomicAdd(count, 1)] = row;
    }
}

// ---------- kernel 2: LDS-free, barrier-free direct-VGPR MFMA GEMM --------------
// 64x64 tile, K=256 straight-line. Each wave owns a 32x32 sub-tile; fragments
// for the whole K extent live in VGPRs (af[2][8], bg[2][8] = 128 VGPRs).
// __launch_bounds__(256, 1): allow up to 512 VGPRs so the compiler KEEPS the
// fragment arrays resident and batches all 32 loads in flight (R5 failed with
// the default occupancy target: VGPR_Count=40 -> rolled 1-outstanding chain).
__global__ __launch_bounds__(256, 1)
void gemm_kernel(const __bf16* __restrict__ zh,
                 const int* __restrict__ flags, const int* __restrict__ onelist,
                 const int* __restrict__ count,
                 float* __restrict__ pos_sum, float* __restrict__ all_sum) {
    const int n = *count;
    const int rowTiles = (n + TIR - 1) / TIR;
    const int totalTiles = rowTiles * COLT;

    const int t = threadIdx.x;
    const int lane = t & 63;
    const int w = t >> 6;
    const int wr = (w >> 1) * 32, wc = (w & 1) * 32;  // wave origin in 64x64 tile
    const int lm = lane & 15, lq = lane >> 4;

    for (int tile = blockIdx.x; tile < totalTiles; tile += gridDim.x) {
        const int rowBase = (tile >> 7) * TIR;        // COLT == 128
        const int colBase = (tile & (COLT - 1)) * TJC;

        // fragment base pointers: A rows gathered via onelist, B rows contiguous
        const __bf16* aRow[2];
        #pragma unroll
        for (int a = 0; a < 2; ++a) {
            const int slot = rowBase + wr + a * 16 + lm;
            const int g = (slot < n) ? onelist[slot] : 0;
            aRow[a] = zh + (size_t)g * DIMS + lq * 8;
        }
        const __bf16* bRow[2];
        #pragma unroll
        for (int b = 0; b < 2; ++b)
            bRow[b] = zh + (size_t)(colBase + wc + b * 16 + lm) * DIMS + lq * 8;

        // load ALL fragments for K=256: 32 x dwordx4 per thread, all in flight
        bf16x8 af[2][8], bg[2][8];
        #pragma unroll
        for (int ks = 0; ks < 8; ++ks) {
            #pragma unroll
            for (int a = 0; a < 2; ++a)
                af[a][ks] = *reinterpret_cast<const bf16x8*>(aRow[a] + ks * 32);
            #pragma unroll
            for (int b = 0; b < 2; ++b)
                bg[b][ks] = *reinterpret_cast<const bf16x8*>(bRow[b] + ks * 32);
        }

        f32x4 acc[2][2];
        #pragma unroll
        for (int a = 0; a < 2; ++a)
            #pragma unroll
            for (int b = 0; b < 2; ++b)
                acc[a][b] = (f32x4){0.f, 0.f, 0.f, 0.f};

        #pragma unroll
        for (int ks = 0; ks < 8; ++ks)
            #pragma unroll
            for (int a = 0; a < 2; ++a)
                #pragma unroll
                for (int b = 0; b < 2; ++b)
                    acc[a][b] = __builtin_amdgcn_mfma_f32_16x16x32_bf16(
                        af[a][ks], bg[b][ks], acc[a][b], 0, 0, 0);

        // -------- fused epilogue: exp, diag/pos masks, per-row sums, atomics ----
        int flb[2];
        #pragma unroll
        for (int b = 0; b < 2; ++b) flb[b] = flags[colBase + wc + b * 16 + lm];
        const int jg0 = colBase + wc + lm;

        #pragma unroll
        for (int a = 0; a < 2; ++a) {
            #pragma unroll
            for (int r = 0; r < 4; ++r) {
                const int il = wr + a * 16 + lq * 4 + r;   // C/D: col=lm, row=lq*4+r
                const int slot = rowBase + il;
                const int g = (slot < n) ? onelist[slot] : -1;
                float sAll = 0.f, sPos = 0.f;
                #pragma unroll
                for (int b = 0; b < 2; ++b) {
                    float e = __expf(acc[a][b][r] * INV_T);
                    if (jg0 + b * 16 == g) e = 0.f;        // zero diagonal
                    sAll += e;
                    if (flb[b]) sPos += e;
                }
                #pragma unroll
                for (int m = 8; m >= 1; m >>= 1) {         // reduce over 16 col-lanes
                    sAll += __shfl_xor(sAll, m);
                    sPos += __shfl_xor(sPos, m);
                }
                if (lm == 0 && slot < n) {
                    atomicAdd(&all_sum[slot], sAll);
                    atomicAdd(&pos_sum[slot], sPos);
                }
            }
        }
    }
}

// ---------- kernel 3: final loss ------------------------------------------------
__global__ __launch_bounds__(256)
void finalize_kernel(const float* __restrict__ pos_sum,
                     const float* __restrict__ all_sum,
                     const int* __restrict__ count,
                     float* __restrict__ out) {
    const int n = *count;
    const int t = threadIdx.x;
    float local = 0.0f;
    if (n >= 2) {
        for (int i = t; i < n; i += 256)
            local += logf(all_sum[i]) - logf(pos_sum[i]);
    }
    #pragma unroll
    for (int o = 32; o >= 1; o >>= 1) local += __shfl_down(local, o, 64);
    __shared__ float wsum[4];
    const int wave = t >> 6, lane = t & 63;
    if (lane == 0) wsum[wave] = local;
    __syncthreads();
    if (t == 0) {
        const float tot = wsum[0] + wsum[1] + wsum[2] + wsum[3];
        out[0] = (n >= 2) ? (tot / (float)n) : 0.0f;
    }
}

// ---------- launcher ------------------------------------------------------------
extern "C" void kernel_launch(void* const* d_in, const int* in_sizes, int n_in,
                              void* d_out, int out_size, void* d_ws, size_t ws_size,
                              hipStream_t stream) {
    // inputs: [0] z_original (unused), [1] z_flowed, [2] attributes
    const float* z_flowed = (const float*)d_in[1];
    const float* attr     = (const float*)d_in[2];
    float* out = (float*)d_out;

    char* ws = (char*)d_ws;
    int*    count   = (int*)ws;                          // 64 B slot
    float*  pos_sum = (float*)(ws + 64);                 // B floats
    float*  all_sum = pos_sum + BROWS;                   // B floats
    int*    flags   = (int*)(all_sum + BROWS);           // B ints
    int*    onelist = flags + BROWS;                     // B ints
    __bf16* zh      = (__bf16*)(onelist + BROWS);        // B*D bf16 (4 MB), 16B-aligned

    hipMemsetAsync(ws, 0, 64, stream);                   // zero count only

    prep_kernel<<<BROWS / 4, 256, 0, stream>>>(z_flowed, attr, zh, flags, onelist,
                                               count, pos_sum, all_sum);

    gemm_kernel<<<GEMM_BLOCKS, 256, 0, stream>>>(zh, flags, onelist, count,
                                                 pos_sum, all_sum);

    finalize_kernel<<<1, 256, 0, stream>>>(pos_sum, all_sum, count, out);
}

// Round 7
// 92.968 us; speedup vs baseline: 1.6703x; 1.6703x over previous
//
#include <hip/hip_runtime.h>
#include <math.h>

#define BROWS 8192
#define DIMS  256
#define ATTRS 4
#define TIR 64              // valid (gathered) rows per tile
#define TJC 64              // cols per tile
#define BK 64               // k-chunk: 64 bf16 = 128 B = 8 x 16B segs
#define NKIT (DIMS / BK)    // 4
#define COLT (BROWS / TJC)  // 128 col tiles
#define GEMM_BLOCKS 1024
#define NCOPY 16            // privatized accumulator copies
#define PART_ROWS 1024      // rows per copy (n~512 expected; fallback if bigger)

typedef __bf16 bf16x8 __attribute__((ext_vector_type(8)));
typedef __bf16 bf16x4 __attribute__((ext_vector_type(4)));
typedef float  f32x4  __attribute__((ext_vector_type(4)));

constexpr float INV_T = 1.0f / 0.07f;

// async global->LDS, 16 B/lane; HW dest = wave-uniform base + lane*16
__device__ __forceinline__ void async_cp16(void* lds, const void* g) {
    __builtin_amdgcn_global_load_lds(
        (const __attribute__((address_space(1))) unsigned int*)g,
        (__attribute__((address_space(3))) unsigned int*)lds,
        16, 0, 0);
}

// ---------- kernel 1: normalize -> bf16, flag all-ones rows, zero partials -----
__global__ __launch_bounds__(256)
void prep_kernel(const float* __restrict__ z, const float* __restrict__ attr,
                 __bf16* __restrict__ zh,
                 int* __restrict__ flags, int* __restrict__ onelist,
                 int* __restrict__ count,
                 float* __restrict__ pos_part, float* __restrict__ all_part) {
    const int t = threadIdx.x;
    const int lane = t & 63;
    const int row = blockIdx.x * 4 + (t >> 6);   // one wave per row

    // zero the privatized partial-sum arrays (first 64 blocks cover 16384 each)
    const int tid = blockIdx.x * 256 + t;
    if (tid < NCOPY * PART_ROWS) {
        pos_part[tid] = 0.0f;
        all_part[tid] = 0.0f;
    }

    const float4 v = *reinterpret_cast<const float4*>(&z[(size_t)row * DIMS + lane * 4]);
    float ss = v.x * v.x + v.y * v.y + v.z * v.z + v.w * v.w;
    #pragma unroll
    for (int m = 32; m >= 1; m >>= 1) ss += __shfl_xor(ss, m);
    const float norm = fmaxf(sqrtf(ss), 1e-12f);

    bf16x4 hv = {(__bf16)(v.x / norm), (__bf16)(v.y / norm),
                 (__bf16)(v.z / norm), (__bf16)(v.w / norm)};
    *reinterpret_cast<bf16x4*>(&zh[(size_t)row * DIMS + lane * 4]) = hv;

    if (lane == 0) {
        const float4 a = *reinterpret_cast<const float4*>(&attr[(size_t)row * ATTRS]);
        const bool one = (a.x == 1.0f) && (a.y == 1.0f) && (a.z == 1.0f) && (a.w == 1.0f);
        flags[row] = one ? 1 : 0;
        if (one) onelist[atomicAdd(count, 1)] = row;
    }
}

// ---------- kernel 2: bf16 MFMA GEMM, async-LDS dbuf, 4 blocks/CU ---------------
__global__ __launch_bounds__(256, 4)
void gemm_kernel(const __bf16* __restrict__ zh,
                 const int* __restrict__ flags, const int* __restrict__ onelist,
                 const int* __restrict__ count,
                 float* __restrict__ pos_part, float* __restrict__ all_part) {
    const int n = *count;
    const int rowTiles = (n + TIR - 1) / TIR;
    const int totalTiles = rowTiles * COLT;

    __shared__ __align__(16) __bf16 sA[2][TIR][BK];   // 16 KB
    __shared__ __align__(16) __bf16 sB[2][TJC][BK];   // 16 KB

    const int t = threadIdx.x;
    const int lane = t & 63;
    const int w = t >> 6;
    const int wr = (w >> 1) * 32, wc = (w & 1) * 32;  // wave origin in 64x64 tile
    const int lm = lane & 15, lq = lane >> 4;

    // staging: wave-instr covers 8 rows x 128 B; XOR seg swizzle on the GLOBAL
    // side (LDS dest must stay lane-linear): seg fetched = (l&7)^(l>>3).
    const int srow8 = lane >> 3;
    const size_t sgb = (size_t)(((lane & 7) ^ srow8) * 16);
    const char* zhB = (const char*)zh;

    // privatized accumulator base (fallback to single copy if n too large)
    const int partBase = (n <= PART_ROWS) ? (int)(blockIdx.x & (NCOPY - 1)) * PART_ROWS : 0;

    for (int tile = blockIdx.x; tile < totalTiles; tile += gridDim.x) {
        const int rowBase = (tile >> 7) * TIR;        // COLT == 128
        const int colBase = (tile & (COLT - 1)) * TJC;

        size_t aOff[2], bOff[2];
        #pragma unroll
        for (int h = 0; h < 2; ++h) {
            const int slot = rowBase + w * 16 + h * 8 + srow8;
            const int g = (slot < n) ? onelist[slot] : 0;
            aOff[h] = (size_t)g * 512 + sgb;
            const int r = colBase + w * 16 + h * 8 + srow8;
            bOff[h] = (size_t)r * 512 + sgb;
        }

        f32x4 acc[2][2];
        #pragma unroll
        for (int a = 0; a < 2; ++a)
            #pragma unroll
            for (int b = 0; b < 2; ++b)
                acc[a][b] = (f32x4){0.f, 0.f, 0.f, 0.f};

        auto stage = [&](int buf, int kbyte) {
            #pragma unroll
            for (int h = 0; h < 2; ++h) {
                async_cp16((char*)&sA[buf][w * 16 + h * 8][0] + lane * 16,
                           zhB + aOff[h] + kbyte);
                async_cp16((char*)&sB[buf][w * 16 + h * 8][0] + lane * 16,
                           zhB + bOff[h] + kbyte);
            }
        };

        stage(0, 0);
        __syncthreads();                              // buf0 landed

        for (int it = 0; it < NKIT; ++it) {
            const int cur = it & 1;
            if (it + 1 < NKIT) stage(cur ^ 1, (it + 1) * BK * 2);

            const int segx = lm & 7;                  // R&7 == lm&7 for all frags
            #pragma unroll
            for (int ks = 0; ks < 2; ++ks) {
                bf16x8 af[2], bf_[2];
                #pragma unroll
                for (int a = 0; a < 2; ++a)
                    af[a] = *reinterpret_cast<const bf16x8*>(
                        &sA[cur][wr + a * 16 + lm][((ks * 4 + lq) ^ segx) * 8]);
                #pragma unroll
                for (int b = 0; b < 2; ++b)
                    bf_[b] = *reinterpret_cast<const bf16x8*>(
                        &sB[cur][wc + b * 16 + lm][((ks * 4 + lq) ^ segx) * 8]);
                #pragma unroll
                for (int a = 0; a < 2; ++a)
                    #pragma unroll
                    for (int b = 0; b < 2; ++b)
                        acc[a][b] = __builtin_amdgcn_mfma_f32_16x16x32_bf16(
                            af[a], bf_[b], acc[a][b], 0, 0, 0);
            }
            __syncthreads();   // readers done before overwrite; drains next loads
        }

        // -------- fused epilogue: exp, diag/pos masks, per-row sums, atomics ----
        int flb[2];
        #pragma unroll
        for (int b = 0; b < 2; ++b) flb[b] = flags[colBase + wc + b * 16 + lm];
        const int jg0 = colBase + wc + lm;

        #pragma unroll
        for (int a = 0; a < 2; ++a) {
            #pragma unroll
            for (int r = 0; r < 4; ++r) {
                const int il = wr + a * 16 + lq * 4 + r;   // C/D: col=lm, row=lq*4+r
                const int slot = rowBase + il;
                const int g = (slot < n) ? onelist[slot] : -1;
                float sAll = 0.f, sPos = 0.f;
                #pragma unroll
                for (int b = 0; b < 2; ++b) {
                    float e = __expf(acc[a][b][r] * INV_T);
                    if (jg0 + b * 16 == g) e = 0.f;        // zero diagonal
                    sAll += e;
                    if (flb[b]) sPos += e;
                }
                #pragma unroll
                for (int m = 8; m >= 1; m >>= 1) {         // reduce over 16 col-lanes
                    sAll += __shfl_xor(sAll, m);
                    sPos += __shfl_xor(sPos, m);
                }
                if (lm == 0 && slot < n) {
                    atomicAdd(&all_part[partBase + slot], sAll);
                    atomicAdd(&pos_part[partBase + slot], sPos);
                }
            }
        }
    }
}

// ---------- kernel 3: final loss (sums the NCOPY privatized partials) ----------
__global__ __launch_bounds__(256)
void finalize_kernel(const float* __restrict__ pos_part,
                     const float* __restrict__ all_part,
                     const int* __restrict__ count,
                     float* __restrict__ out) {
    const int n = *count;
    const int t = threadIdx.x;
    float local = 0.0f;
    if (n >= 2) {
        for (int i = t; i < n; i += 256) {
            float p = 0.f, a = 0.f;
            if (n <= PART_ROWS) {
                #pragma unroll
                for (int c = 0; c < NCOPY; ++c) {
                    p += pos_part[c * PART_ROWS + i];
                    a += all_part[c * PART_ROWS + i];
                }
            } else {
                p = pos_part[i];
                a = all_part[i];
            }
            local += logf(a) - logf(p);
        }
    }
    #pragma unroll
    for (int o = 32; o >= 1; o >>= 1) local += __shfl_down(local, o, 64);
    __shared__ float wsum[4];
    const int wave = t >> 6, lane = t & 63;
    if (lane == 0) wsum[wave] = local;
    __syncthreads();
    if (t == 0) {
        const float tot = wsum[0] + wsum[1] + wsum[2] + wsum[3];
        out[0] = (n >= 2) ? (tot / (float)n) : 0.0f;
    }
}

// ---------- launcher ------------------------------------------------------------
extern "C" void kernel_launch(void* const* d_in, const int* in_sizes, int n_in,
                              void* d_out, int out_size, void* d_ws, size_t ws_size,
                              hipStream_t stream) {
    // inputs: [0] z_original (unused), [1] z_flowed, [2] attributes
    const float* z_flowed = (const float*)d_in[1];
    const float* attr     = (const float*)d_in[2];
    float* out = (float*)d_out;

    char* ws = (char*)d_ws;
    int*    count    = (int*)ws;                              // 64 B slot
    float*  pos_part = (float*)(ws + 64);                     // NCOPY*PART_ROWS floats
    float*  all_part = pos_part + NCOPY * PART_ROWS;          // NCOPY*PART_ROWS floats
    int*    flags    = (int*)(all_part + NCOPY * PART_ROWS);  // B ints
    int*    onelist  = flags + BROWS;                         // B ints
    __bf16* zh       = (__bf16*)(onelist + BROWS);            // B*D bf16 (4 MB)

    hipMemsetAsync(ws, 0, 64, stream);                        // zero count only

    prep_kernel<<<BROWS / 4, 256, 0, stream>>>(z_flowed, attr, zh, flags, onelist,
                                               count, pos_part, all_part);

    gemm_kernel<<<GEMM_BLOCKS, 256, 0, stream>>>(zh, flags, onelist, count,
                                                 pos_part, all_part);

    finalize_kernel<<<1, 256, 0, stream>>>(pos_part, all_part, count, out);
}